// Round 1
// baseline (220.874 us; speedup 1.0000x reference)
//
#include <hip/hip_runtime.h>
#include <hip/hip_bf16.h>
#include <cstdint>

// Head attention: B=16, T=2048, E=256, H=64, causal, fp32 I/O.
// Plan: prep_w (W -> bf16, transposed, q-scale folded) -> proj (q,k,v -> qh,kh,vt bf16)
//       -> flash-attn (MFMA 16x16x32 bf16, online softmax).

#define NB 16
#define TT 2048
#define EE 256
#define HH 64

using bf16x8 = __attribute__((ext_vector_type(8))) __bf16;
using f32x4  = __attribute__((ext_vector_type(4))) float;
using u16x4  = __attribute__((ext_vector_type(4))) unsigned short;

static __device__ __forceinline__ unsigned short f2b(float f) {
  return __builtin_bit_cast(unsigned short, (__bf16)f);
}

// ---------------- kernel 0: W -> wt[3][64][256] bf16 (transposed, q pre-scaled) ----
__global__ __launch_bounds__(256) void prep_w_kernel(
    const float* __restrict__ Wq, const float* __restrict__ Wk,
    const float* __restrict__ Wv, unsigned short* __restrict__ wt) {
  int o = blockIdx.x * 256 + threadIdx.x;          // 0 .. 3*64*256-1
  int p = o >> 14, rem = o & 16383;
  int n = rem >> 8, kk = rem & 255;                // wt[p][n][kk] = W_p[kk][n]
  const float* W = (p == 0) ? Wq : ((p == 1) ? Wk : Wv);
  float val = W[kk * HH + n];
  if (p == 0) val *= 0.0625f;                      // fold 256^-0.5 into qh
  wt[o] = f2b(val);
}

// ---------------- kernel 1: projections -------------------------------------------
// grid (512, 3): 64 rows x 64 cols per block, K=256. 4 waves, each 16 rows.
// A staged in LDS bf16 with XOR swizzle; B-frags direct from global wt (L1/L2-hot).
// p==2 (v) stores transposed vt[B][64][T] via LDS bounce for coalesced writes.
__global__ __launch_bounds__(256) void proj_kernel(
    const float* __restrict__ qi, const float* __restrict__ ki, const float* __restrict__ vi,
    const unsigned short* __restrict__ wt,
    unsigned short* __restrict__ qh, unsigned short* __restrict__ kh,
    unsigned short* __restrict__ vt) {
  const int p = blockIdx.y;
  const int row0 = blockIdx.x * 64;
  const float* __restrict__ src = (p == 0) ? qi : ((p == 1) ? ki : vi);
  const unsigned short* __restrict__ wp = wt + p * (HH * EE);

  __shared__ unsigned short A[64 * EE];            // 32 KB, swizzled bf16 [row][k]
  const int tid = threadIdx.x;

  // stage A: 4096 float4 chunks, coalesced; convert to bf16; swizzled 8B LDS writes
  #pragma unroll
  for (int i = 0; i < 16; ++i) {
    int c = i * 256 + tid;
    int r = c >> 6, d4 = c & 63;
    float4 f = *reinterpret_cast<const float4*>(src + (size_t)(row0 + r) * EE + d4 * 4);
    u16x4 h = { f2b(f.x), f2b(f.y), f2b(f.z), f2b(f.w) };
    int byte = r * 512 + ((d4 * 8) ^ ((r & 7) << 4));
    *reinterpret_cast<u16x4*>(reinterpret_cast<char*>(A) + byte) = h;
  }
  __syncthreads();

  const int wv = tid >> 6, lane = tid & 63, lr = lane & 15, lg = lane >> 4;
  f32x4 acc[4] = {};
  const int arow = wv * 16 + lr;
  const char* Abase = reinterpret_cast<const char*>(A) + arow * 512;
  #pragma unroll
  for (int k0 = 0; k0 < EE; k0 += 32) {
    bf16x8 af = *reinterpret_cast<const bf16x8*>(
        Abase + ((k0 * 2 + lg * 16) ^ ((arow & 7) << 4)));
    #pragma unroll
    for (int nt = 0; nt < 4; ++nt) {
      bf16x8 bfm = *reinterpret_cast<const bf16x8*>(wp + (nt * 16 + lr) * EE + k0 + lg * 8);
      acc[nt] = __builtin_amdgcn_mfma_f32_16x16x32_bf16(af, bfm, acc[nt], 0, 0, 0);
    }
  }

  if (p < 2) {
    unsigned short* dst = (p == 0) ? qh : kh;
    #pragma unroll
    for (int nt = 0; nt < 4; ++nt)
      #pragma unroll
      for (int r = 0; r < 4; ++r) {
        int grow = row0 + wv * 16 + lg * 4 + r;    // C/D: row = 4*(l>>4)+r, col = l&15
        dst[(size_t)grow * HH + nt * 16 + lr] = f2b(acc[nt][r]);
      }
  } else {
    __syncthreads();                               // A reads done; reuse as bounce
    #pragma unroll
    for (int nt = 0; nt < 4; ++nt)
      #pragma unroll
      for (int r = 0; r < 4; ++r) {
        int col = nt * 16 + lr;
        int trow = wv * 16 + lg * 4 + r;
        *reinterpret_cast<unsigned short*>(reinterpret_cast<char*>(A)
            + col * 128 + ((trow * 2) ^ ((col & 7) << 4))) = f2b(acc[nt][r]);
      }
    __syncthreads();
    const int bb = row0 >> 11, t0 = row0 & 2047;
    #pragma unroll
    for (int i = 0; i < 2; ++i) {
      int ch = i * 256 + tid;
      int col = ch >> 3, ro = (ch & 7) * 8;
      bf16x8 val = *reinterpret_cast<const bf16x8*>(reinterpret_cast<char*>(A)
          + col * 128 + ((ro * 2) ^ ((col & 7) << 4)));
      *reinterpret_cast<bf16x8*>(vt + (size_t)(bb * 64 + col) * TT + t0 + ro) = val;
    }
  }
}

// ---------------- kernel 2: causal flash attention --------------------------------
// 512 blocks (16 batches x 32 q-tiles, paired j/(31-j) for load balance).
// 4 waves x 16 q-rows; KV tiles of 64 staged in LDS (XOR-swizzled); online softmax.
__global__ __launch_bounds__(256) void attn_kernel(
    const unsigned short* __restrict__ qh, const unsigned short* __restrict__ kh,
    const unsigned short* __restrict__ vt, float* __restrict__ out) {
  __shared__ unsigned short K_lds[64 * 64];        // [key][dim] swizzled
  __shared__ unsigned short V_lds[64 * 64];        // [dim][key] swizzled
  __shared__ unsigned short P_lds[4 * 16 * 64];    // per-wave [row][key] swizzled

  const int bid = blockIdx.x;
  const int u = bid >> 1, odd = bid & 1;
  const int b = u >> 4, j = u & 15;
  const int qt = odd ? j : 31 - j;
  const int q0 = qt * 64;
  const int tid = threadIdx.x, wv = tid >> 6, lane = tid & 63, lr = lane & 15, lg = lane >> 4;

  bf16x8 qf[2];                                    // A-frags: row = l&15, k = 8*(l>>4)+j
  {
    const unsigned short* qrow = qh + ((size_t)b * TT + q0 + wv * 16 + lr) * HH;
    qf[0] = *reinterpret_cast<const bf16x8*>(qrow + lg * 8);
    qf[1] = *reinterpret_cast<const bf16x8*>(qrow + 32 + lg * 8);
  }

  f32x4 oa[4] = {};
  float m[4] = {-__builtin_inff(), -__builtin_inff(), -__builtin_inff(), -__builtin_inff()};
  float ld[4] = {0.f, 0.f, 0.f, 0.f};

  for (int kt = 0; kt <= qt; ++kt) {
    __syncthreads();                               // prior iter's LDS reads done
    #pragma unroll
    for (int i = 0; i < 2; ++i) {                  // stage K and V tiles (8 KB each)
      int ch = i * 256 + tid;
      int rr = ch >> 3, off8 = (ch & 7) * 8;
      bf16x8 kvv = *reinterpret_cast<const bf16x8*>(
          kh + ((size_t)b * TT + kt * 64 + rr) * HH + off8);
      *reinterpret_cast<bf16x8*>(reinterpret_cast<char*>(K_lds)
          + rr * 128 + ((off8 * 2) ^ ((rr & 7) << 4))) = kvv;
      bf16x8 vvv = *reinterpret_cast<const bf16x8*>(
          vt + (size_t)(b * 64 + rr) * TT + kt * 64 + off8);
      *reinterpret_cast<bf16x8*>(reinterpret_cast<char*>(V_lds)
          + rr * 128 + ((off8 * 2) ^ ((rr & 7) << 4))) = vvv;
    }
    __syncthreads();

    // S = Q K^T : 8 MFMAs; C/D row = q-row (4*lg+r), col = key (nt*16+lr)
    f32x4 s[4] = {};
    #pragma unroll
    for (int ks = 0; ks < 2; ++ks)
      #pragma unroll
      for (int nt = 0; nt < 4; ++nt) {
        int key = nt * 16 + lr;
        bf16x8 kf = *reinterpret_cast<const bf16x8*>(reinterpret_cast<const char*>(K_lds)
            + key * 128 + ((ks * 64 + lg * 16) ^ ((key & 7) << 4)));
        s[nt] = __builtin_amdgcn_mfma_f32_16x16x32_bf16(qf[ks], kf, s[nt], 0, 0, 0);
      }

    if (kt == qt) {                                // causal mask on the diagonal tile
      #pragma unroll
      for (int nt = 0; nt < 4; ++nt)
        #pragma unroll
        for (int r = 0; r < 4; ++r)
          if (nt * 16 + lr > wv * 16 + lg * 4 + r) s[nt][r] = -__builtin_inff();
    }

    // online softmax: row stats live in the 16-lane (col) group; butterfly reduce
    float corr[4];
    #pragma unroll
    for (int r = 0; r < 4; ++r) {
      float t = fmaxf(fmaxf(s[0][r], s[1][r]), fmaxf(s[2][r], s[3][r]));
      t = fmaxf(t, __shfl_xor(t, 1));
      t = fmaxf(t, __shfl_xor(t, 2));
      t = fmaxf(t, __shfl_xor(t, 4));
      t = fmaxf(t, __shfl_xor(t, 8));
      float mn = fmaxf(m[r], t);
      corr[r] = __expf(m[r] - mn);
      m[r] = mn;
    }
    #pragma unroll
    for (int nt = 0; nt < 4; ++nt)
      #pragma unroll
      for (int r = 0; r < 4; ++r)
        s[nt][r] = __expf(s[nt][r] - m[r]);
    #pragma unroll
    for (int r = 0; r < 4; ++r) {
      float t = s[0][r] + s[1][r] + s[2][r] + s[3][r];
      t += __shfl_xor(t, 1);
      t += __shfl_xor(t, 2);
      t += __shfl_xor(t, 4);
      t += __shfl_xor(t, 8);
      ld[r] = ld[r] * corr[r] + t;
      oa[0][r] *= corr[r]; oa[1][r] *= corr[r]; oa[2][r] *= corr[r]; oa[3][r] *= corr[r];
    }

    // P: acc layout -> A-frag layout via per-wave swizzled LDS region
    char* pbase = reinterpret_cast<char*>(P_lds) + wv * 2048;
    #pragma unroll
    for (int nt = 0; nt < 4; ++nt)
      #pragma unroll
      for (int r = 0; r < 4; ++r) {
        int row = lg * 4 + r;
        *reinterpret_cast<unsigned short*>(pbase
            + row * 128 + (((nt * 16 + lr) * 2) ^ ((row & 7) << 4))) = f2b(s[nt][r]);
      }

    // O += P V : 8 MFMAs
    #pragma unroll
    for (int ks = 0; ks < 2; ++ks) {
      bf16x8 pf = *reinterpret_cast<const bf16x8*>(
          pbase + lr * 128 + ((ks * 64 + lg * 16) ^ ((lr & 7) << 4)));
      #pragma unroll
      for (int nt = 0; nt < 4; ++nt) {
        int dim = nt * 16 + lr;
        bf16x8 vf = *reinterpret_cast<const bf16x8*>(reinterpret_cast<const char*>(V_lds)
            + dim * 128 + ((ks * 64 + lg * 16) ^ ((dim & 7) << 4)));
        oa[nt] = __builtin_amdgcn_mfma_f32_16x16x32_bf16(pf, vf, oa[nt], 0, 0, 0);
      }
    }
  }

  #pragma unroll
  for (int r = 0; r < 4; ++r) {
    float inv = 1.0f / ld[r];
    #pragma unroll
    for (int nt = 0; nt < 4; ++nt) {
      int row = q0 + wv * 16 + lg * 4 + r;
      out[((size_t)b * TT + row) * HH + nt * 16 + lr] = oa[nt][r] * inv;
    }
  }
}

// ---------------- launcher --------------------------------------------------------
extern "C" void kernel_launch(void* const* d_in, const int* in_sizes, int n_in,
                              void* d_out, int out_size, void* d_ws, size_t ws_size,
                              hipStream_t stream) {
  const float* q  = (const float*)d_in[0];
  const float* k  = (const float*)d_in[1];
  const float* v  = (const float*)d_in[2];
  // d_in[3] = mask (tril) — causal handled analytically, never read
  const float* Wq = (const float*)d_in[4];
  const float* Wk = (const float*)d_in[5];
  const float* Wv = (const float*)d_in[6];

  char* ws = (char*)d_ws;
  unsigned short* wt = (unsigned short*)ws;                      // 3*64*256   (96 KB)
  unsigned short* qh = (unsigned short*)(ws + 98304);            // [B*T][64] bf16, pre-scaled
  unsigned short* kh = qh + (size_t)NB * TT * HH;                // [B*T][64] bf16
  unsigned short* vt = kh + (size_t)NB * TT * HH;                // [B][64][T] bf16
  float* out = (float*)d_out;

  prep_w_kernel<<<192, 256, 0, stream>>>(Wq, Wk, Wv, wt);
  proj_kernel<<<dim3(512, 3), 256, 0, stream>>>(q, k, v, wt, qh, kh, vt);
  attn_kernel<<<512, 256, 0, stream>>>(qh, kh, vt, out);
}